// Round 3
// baseline (483.544 us; speedup 1.0000x reference)
//
#include <hip/hip_runtime.h>

#define DDIM 2048
#define SLEN 2048
#define BSZ 4
#define NTOK (BSZ*SLEN)        // 8192
#define RANK 160
#define SROWS 66               // 2 + HEAD_SIZE
#define OUT_MAIN ((size_t)NTOK*5*DDIM)   // 83,886,080 floats
#define STATE_N (BSZ*SROWS*DDIM)         // 540,672 floats

typedef __bf16 bf16x8 __attribute__((ext_vector_type(8)));
typedef float  f32x4  __attribute__((ext_vector_type(4)));
typedef unsigned short us8 __attribute__((ext_vector_type(8)));
typedef unsigned short us4 __attribute__((ext_vector_type(4)));

__device__ __forceinline__ unsigned short f2bf(float f) {
    unsigned b = __float_as_uint(f);
    return (unsigned short)((b + 0x7fffu + ((b >> 16) & 1u)) >> 16);  // RNE
}

// ---- prep: blocks [0,320) transpose W1, [320,640) transpose W2, [640,1168) state copy
__global__ __launch_bounds__(256) void k_prep(
        const float* __restrict__ x,
        const float* __restrict__ state,
        const int* __restrict__ pi,
        const float* __restrict__ w1,
        const float* __restrict__ w2,
        float* __restrict__ out_state,
        unsigned short* __restrict__ w1t,
        unsigned short* __restrict__ w2t) {
    __shared__ float t[32 * 33];
    int bid = blockIdx.x, tid = threadIdx.x;
    if (bid < 320) {
        // W1 [2048,160] f32 -> W1T [160,2048] bf16, 32x32 LDS tile
        int kt = bid / 5;
        int k0 = kt * 32, n0 = (bid - kt * 5) * 32;
        int rr = tid >> 3, cc = (tid & 7) * 4;
        f32x4 v = *(const f32x4*)(w1 + (size_t)(k0 + rr) * RANK + n0 + cc);
        #pragma unroll
        for (int j = 0; j < 4; j++) t[(cc + j) * 33 + rr] = v[j];  // t[n_local][k_local]
        __syncthreads();
        us4 o;
        #pragma unroll
        for (int j = 0; j < 4; j++) o[j] = f2bf(t[rr * 33 + cc + j]);
        *(us4*)(w1t + (size_t)(n0 + rr) * DDIM + k0 + cc) = o;
    } else if (bid < 640) {
        // W2 [5,32,2048] f32 -> W2T [5,2048,32] bf16, 32x32 LDS tile per f
        int b2 = bid - 320;
        int f = b2 >> 6, d0 = (b2 & 63) * 32;
        int rr = tid >> 3, cc = (tid & 7) * 4;       // rr = k_local, cc = d_local
        f32x4 v = *(const f32x4*)(w2 + (size_t)(f * 32 + rr) * DDIM + d0 + cc);
        #pragma unroll
        for (int j = 0; j < 4; j++) t[(cc + j) * 33 + rr] = v[j];  // t[d_local][k_local]
        __syncthreads();
        us4 o;
        #pragma unroll
        for (int j = 0; j < 4; j++) o[j] = f2bf(t[rr * 33 + cc + j]);  // rr = d_local now
        *(us4*)(w2t + ((size_t)(f * DDIM) + d0 + rr) * 32 + cc) = o;
    } else {
        // state copy, overwrite row i1 with x[:, S-1, :]
        int idx = ((bid - 640) * 256 + tid) * 4;     // STATE_N = 528*256*4 exactly
        int i1 = 66 * pi[0] + 1;
        int b   = idx / (SROWS * DDIM);
        int rem = idx - b * (SROWS * DDIM);
        int row = rem / DDIM;
        int d   = rem - row * DDIM;
        f32x4 v;
        if (row == i1) v = *(const f32x4*)(x + ((size_t)(b * SLEN + SLEN - 1)) * DDIM + d);
        else           v = *(const f32x4*)(state + idx);
        *(f32x4*)(out_state + idx) = v;
    }
}

// ---- fused: GEMM1 (xxx in LDS) + GEMM2 + epilogue, one kernel ----
// block = 16 tokens, 320 threads = 5 waves.
// Phase 1: wave w computes xxx cols [w*32, w*32+32). Phase 2: wave w = feature f.
__global__ __launch_bounds__(320, 4) void k_fused(
        const float* __restrict__ x,
        const float* __restrict__ state,
        const float* __restrict__ tmx,
        const unsigned short* __restrict__ w1t,
        const unsigned short* __restrict__ w2t,
        const float* __restrict__ mk,
        const float* __restrict__ mw,
        const float* __restrict__ mv,
        const float* __restrict__ mr,
        const float* __restrict__ mg,
        const int* __restrict__ pi,
        float* __restrict__ out) {
    __shared__ unsigned short sxw[16 * 136];   // staging tile [16 tok][128 K] bf16
    __shared__ unsigned short xxxt[16 * 168];  // xxx tile [16 tok][160] bf16, pad 168

    int tid  = threadIdx.x;
    int w    = tid >> 6, lane = tid & 63;
    int q    = lane >> 4, nl = lane & 15;
    int m0   = blockIdx.x * 16;
    int b    = m0 >> 11;
    int i1   = 66 * pi[0] + 1;

    // ---------------- phase 1: GEMM1 ----------------
    int srow = tid >> 4;            // 0..15 (tid < 256)
    int scol = (tid & 15) * 8;      // 0..120
    const float* xrow = nullptr;
    const float* prow = nullptr;
    if (tid < 256) {
        int m = m0 + srow;
        int s = m & (SLEN - 1);
        xrow = x + (size_t)m * DDIM;
        prow = (s == 0) ? (state + (size_t)(b * SROWS + i1) * DDIM)
                        : (x + (size_t)(m - 1) * DDIM);
    }

    f32x4 acc0 = (f32x4){0.f, 0.f, 0.f, 0.f};
    f32x4 acc1 = (f32x4){0.f, 0.f, 0.f, 0.f};

    for (int k0 = 0; k0 < DDIM; k0 += 128) {
        if (tid < 256) {
            f32x4 xa = *(const f32x4*)(xrow + k0 + scol);
            f32x4 xb = *(const f32x4*)(xrow + k0 + scol + 4);
            f32x4 pa = *(const f32x4*)(prow + k0 + scol);
            f32x4 pb = *(const f32x4*)(prow + k0 + scol + 4);
            f32x4 ta = *(const f32x4*)(tmx  + k0 + scol);
            f32x4 tb = *(const f32x4*)(tmx  + k0 + scol + 4);
            us8 o;
            #pragma unroll
            for (int j = 0; j < 4; j++) {
                o[j]     = f2bf(xa[j] + (pa[j] - xa[j]) * ta[j]);
                o[j + 4] = f2bf(xb[j] + (pb[j] - xb[j]) * tb[j]);
            }
            *(us8*)(sxw + srow * 136 + scol) = o;
        }
        __syncthreads();
        #pragma unroll
        for (int kk = 0; kk < 128; kk += 32) {
            bf16x8 a  = *(const bf16x8*)(sxw + nl * 136 + kk + q * 8);
            bf16x8 b0 = *(const bf16x8*)(w1t + (size_t)(w * 32 + nl) * DDIM + k0 + kk + q * 8);
            bf16x8 b1 = *(const bf16x8*)(w1t + (size_t)(w * 32 + 16 + nl) * DDIM + k0 + kk + q * 8);
            acc0 = __builtin_amdgcn_mfma_f32_16x16x32_bf16(a, b0, acc0, 0, 0, 0);
            acc1 = __builtin_amdgcn_mfma_f32_16x16x32_bf16(a, b1, acc1, 0, 0, 0);
        }
        __syncthreads();
    }

    // xxx -> LDS (C layout: row tok = q*4+r, col = nl)
    #pragma unroll
    for (int r = 0; r < 4; r++) {
        xxxt[(q * 4 + r) * 168 + w * 32 + nl]      = f2bf(tanhf(acc0[r]));
        xxxt[(q * 4 + r) * 168 + w * 32 + 16 + nl] = f2bf(tanhf(acc1[r]));
    }
    __syncthreads();

    // ---------------- phase 2: GEMM2 + epilogue, wave w = feature f ----------------
    const float* maa = (w == 0) ? mk : (w == 1) ? mw : (w == 2) ? mv
                     : (w == 3) ? mr : mg;
    // A-frag for this wave's feature: lane (q,nl) holds xxx[tok=nl][f*32 + q*8 ..+8]
    bf16x8 af = *(const bf16x8*)(xxxt + nl * 168 + w * 32 + q * 8);

    // per-r row base pointers (tok = q*4 + r)
    const float* xb0; const float* xb1; const float* xb2; const float* xb3;
    const float* pb0; const float* pb1; const float* pb2; const float* pb3;
    float* ob0; float* ob1; float* ob2; float* ob3;
    {
        const float* strow = state + (size_t)(b * SROWS + i1) * DDIM;
        int t0 = q * 4;
        int m_ = m0 + t0;
        xb0 = x + (size_t)m_ * DDIM;
        pb0 = ((m_ & (SLEN - 1)) == 0) ? strow : (x + (size_t)(m_ - 1) * DDIM);
        ob0 = (float*)out + ((size_t)(m_ * 5 + w)) * DDIM;
        m_ = m0 + t0 + 1;
        xb1 = x + (size_t)m_ * DDIM;
        pb1 = x + (size_t)(m_ - 1) * DDIM;   // tok>=1 never hits state row
        ob1 = (float*)out + ((size_t)(m_ * 5 + w)) * DDIM;
        m_ = m0 + t0 + 2;
        xb2 = x + (size_t)m_ * DDIM;
        pb2 = x + (size_t)(m_ - 1) * DDIM;
        ob2 = (float*)out + ((size_t)(m_ * 5 + w)) * DDIM;
        m_ = m0 + t0 + 3;
        xb3 = x + (size_t)m_ * DDIM;
        pb3 = x + (size_t)(m_ - 1) * DDIM;
        ob3 = (float*)out + ((size_t)(m_ * 5 + w)) * DDIM;
    }

    const unsigned short* w2base = w2t + ((size_t)w * DDIM) * 32;

    for (int dT = 0; dT < 16; dT++) {
        int d0 = dT * 128;
        #pragma unroll 2
        for (int dsub = 0; dsub < 8; dsub++) {
            int d = d0 + dsub * 16 + nl;
            bf16x8 bb = *(const bf16x8*)(w2base + (size_t)d * 32 + q * 8);
            f32x4 c = (f32x4){0.f, 0.f, 0.f, 0.f};
            c = __builtin_amdgcn_mfma_f32_16x16x32_bf16(af, bb, c, 0, 0, 0);
            float ma = maa[d];
            {
                float xf = xb0[d], pf = pb0[d];
                __builtin_nontemporal_store(xf + (pf - xf) * (ma + c[0]), ob0 + d);
            }
            {
                float xf = xb1[d], pf = pb1[d];
                __builtin_nontemporal_store(xf + (pf - xf) * (ma + c[1]), ob1 + d);
            }
            {
                float xf = xb2[d], pf = pb2[d];
                __builtin_nontemporal_store(xf + (pf - xf) * (ma + c[2]), ob2 + d);
            }
            {
                float xf = xb3[d], pf = pb3[d];
                __builtin_nontemporal_store(xf + (pf - xf) * (ma + c[3]), ob3 + d);
            }
        }
    }
}

extern "C" void kernel_launch(void* const* d_in, const int* in_sizes, int n_in,
                              void* d_out, int out_size, void* d_ws, size_t ws_size,
                              hipStream_t stream) {
    const float* x   = (const float*)d_in[0];
    const float* st  = (const float*)d_in[1];
    const float* tmx = (const float*)d_in[2];
    const float* w1  = (const float*)d_in[3];
    const float* w2  = (const float*)d_in[4];
    const float* mk  = (const float*)d_in[5];
    const float* mw  = (const float*)d_in[6];
    const float* mv  = (const float*)d_in[7];
    const float* mr  = (const float*)d_in[8];
    const float* mg  = (const float*)d_in[9];
    const int* pi    = (const int*)d_in[10];
    float* out = (float*)d_out;

    // ws usage: 1,310,720 bytes
    char* ws = (char*)d_ws;
    unsigned short* w1t = (unsigned short*)(ws);            // 655,360 B
    unsigned short* w2t = (unsigned short*)(ws + 655360);   // 655,360 B

    k_prep<<<1168, 256, 0, stream>>>(x, st, pi, w1, w2, out + OUT_MAIN, w1t, w2t);
    k_fused<<<512, 320, 0, stream>>>(x, st, tmx, w1t, w2t,
                                     mk, mw, mv, mr, mg, pi, out);
}

// Round 4
// 427.606 us; speedup vs baseline: 1.1308x; 1.1308x over previous
//
#include <hip/hip_runtime.h>

#define DDIM 2048
#define SLEN 2048
#define BSZ 4
#define NTOK (BSZ*SLEN)        // 8192
#define RANK 160
#define SROWS 66               // 2 + HEAD_SIZE
#define OUT_MAIN ((size_t)NTOK*5*DDIM)   // 83,886,080 floats
#define STATE_N (BSZ*SROWS*DDIM)         // 540,672 floats

typedef __bf16 bf16x8 __attribute__((ext_vector_type(8)));
typedef float  f32x4  __attribute__((ext_vector_type(4)));
typedef unsigned short us8 __attribute__((ext_vector_type(8)));
typedef unsigned short us4 __attribute__((ext_vector_type(4)));

__device__ __forceinline__ unsigned short f2bf(float f) {
    unsigned b = __float_as_uint(f);
    return (unsigned short)((b + 0x7fffu + ((b >> 16) & 1u)) >> 16);  // RNE
}

// ---- prep: blocks [0,320) transpose W1, [320,640) transpose W2, [640,1168) state copy
__global__ __launch_bounds__(256) void k_prep(
        const float* __restrict__ x,
        const float* __restrict__ state,
        const int* __restrict__ pi,
        const float* __restrict__ w1,
        const float* __restrict__ w2,
        float* __restrict__ out_state,
        unsigned short* __restrict__ w1t,
        unsigned short* __restrict__ w2t) {
    __shared__ float t[32 * 33];
    int bid = blockIdx.x, tid = threadIdx.x;
    if (bid < 320) {
        // W1 [2048,160] f32 -> W1T [160,2048] bf16, 32x32 LDS tile
        int kt = bid / 5;
        int k0 = kt * 32, n0 = (bid - kt * 5) * 32;
        int rr = tid >> 3, cc = (tid & 7) * 4;
        f32x4 v = *(const f32x4*)(w1 + (size_t)(k0 + rr) * RANK + n0 + cc);
        #pragma unroll
        for (int j = 0; j < 4; j++) t[(cc + j) * 33 + rr] = v[j];  // t[n_local][k_local]
        __syncthreads();
        us4 o;
        #pragma unroll
        for (int j = 0; j < 4; j++) o[j] = f2bf(t[rr * 33 + cc + j]);
        *(us4*)(w1t + (size_t)(n0 + rr) * DDIM + k0 + cc) = o;
    } else if (bid < 640) {
        // W2 [5,32,2048] f32 -> W2T [5,2048,32] bf16, 32x32 LDS tile per f
        int b2 = bid - 320;
        int f = b2 >> 6, d0 = (b2 & 63) * 32;
        int rr = tid >> 3, cc = (tid & 7) * 4;       // rr = k_local, cc = d_local
        f32x4 v = *(const f32x4*)(w2 + (size_t)(f * 32 + rr) * DDIM + d0 + cc);
        #pragma unroll
        for (int j = 0; j < 4; j++) t[(cc + j) * 33 + rr] = v[j];  // t[d_local][k_local]
        __syncthreads();
        us4 o;
        #pragma unroll
        for (int j = 0; j < 4; j++) o[j] = f2bf(t[rr * 33 + cc + j]);  // rr = d_local now
        *(us4*)(w2t + ((size_t)(f * DDIM) + d0 + rr) * 32 + cc) = o;
    } else {
        // state copy, overwrite row i1 with x[:, S-1, :]
        int idx = ((bid - 640) * 256 + tid) * 4;     // STATE_N = 528*256*4 exactly
        int i1 = 66 * pi[0] + 1;
        int b   = idx / (SROWS * DDIM);
        int rem = idx - b * (SROWS * DDIM);
        int row = rem / DDIM;
        int d   = rem - row * DDIM;
        f32x4 v;
        if (row == i1) v = *(const f32x4*)(x + ((size_t)(b * SLEN + SLEN - 1)) * DDIM + d);
        else           v = *(const f32x4*)(state + idx);
        *(f32x4*)(out_state + idx) = v;
    }
}

// ---- GEMM1 fused: xxx = tanh((x + sx*tmx) @ W1), M=8192 K=2048 N=160 ----
// 16-token tile, 640 threads = 10 waves: kh (K-half) x nh (32 cols). 2 blocks/CU.
__global__ __launch_bounds__(640) void k_gemm1f(
        const float* __restrict__ x,
        const float* __restrict__ state,
        const float* __restrict__ tmx,
        const unsigned short* __restrict__ w1t,
        const int* __restrict__ pi,
        unsigned short* __restrict__ xxx) {
    __shared__ unsigned short sxw[16 * 136];   // bf16 [16 tok][128 K], stride 136
    __shared__ float red[10 * 16 * 17];        // K-half partials [10 tiles][16r][16c+pad]
    int tid  = threadIdx.x;
    int w    = tid >> 6, lane = tid & 63;
    int q    = lane >> 4, nl = lane & 15;
    int kh   = (w >= 5) ? 1 : 0;
    int nh   = kh ? (w - 5) : w;
    int m0   = blockIdx.x * 16;
    int b    = m0 >> 11;
    int i1   = 66 * pi[0] + 1;

    // staging: threads 0..511 stage [16 tok x 128 K] per iteration
    int srow = tid >> 5;
    int scol = (tid & 31) * 4;
    const float* xrow = nullptr;
    const float* prow = nullptr;
    if (tid < 512) {
        int m = m0 + srow;
        int s = m & (SLEN - 1);
        xrow = x + (size_t)m * DDIM;
        prow = (s == 0) ? (state + (size_t)(b * SROWS + i1) * DDIM)
                        : (x + (size_t)(m - 1) * DDIM);
    }

    f32x4 acc[2];
    acc[0] = (f32x4){0.f, 0.f, 0.f, 0.f};
    acc[1] = (f32x4){0.f, 0.f, 0.f, 0.f};

    for (int i = 0; i < 16; i++) {
        if (tid < 512) {
            int gc = i * 128 + scol;
            f32x4 xa = *(const f32x4*)(xrow + gc);
            f32x4 pa = *(const f32x4*)(prow + gc);
            f32x4 ta = *(const f32x4*)(tmx  + gc);
            us4 o;
            #pragma unroll
            for (int j = 0; j < 4; j++)
                o[j] = f2bf(xa[j] + (pa[j] - xa[j]) * ta[j]);
            *(us4*)(sxw + srow * 136 + scol) = o;
        }
        __syncthreads();
        #pragma unroll
        for (int kk = 0; kk < 64; kk += 32) {
            bf16x8 a = *(const bf16x8*)(sxw + nl * 136 + kh * 64 + kk + q * 8);
            #pragma unroll
            for (int t = 0; t < 2; t++) {
                bf16x8 bb = *(const bf16x8*)(w1t + (size_t)(nh * 32 + t * 16 + nl) * DDIM
                                             + i * 128 + kh * 64 + kk + q * 8);
                acc[t] = __builtin_amdgcn_mfma_f32_16x16x32_bf16(a, bb, acc[t], 0, 0, 0);
            }
        }
        __syncthreads();
    }

    if (kh) {
        #pragma unroll
        for (int t = 0; t < 2; t++)
            #pragma unroll
            for (int r = 0; r < 4; r++)
                red[((nh * 2 + t) * 16 + q * 4 + r) * 17 + nl] = acc[t][r];
    }
    __syncthreads();
    if (!kh) {
        #pragma unroll
        for (int t = 0; t < 2; t++)
            #pragma unroll
            for (int r = 0; r < 4; r++) {
                float v = acc[t][r] + red[((nh * 2 + t) * 16 + q * 4 + r) * 17 + nl];
                xxx[(size_t)(m0 + q * 4 + r) * RANK + nh * 32 + t * 16 + nl]
                    = f2bf(tanhf(v));
            }
    }
}

// ---- GEMM2 (K=32) + epilogue, software-pipelined, NT stores ----
// block: 16 tokens x 128 d x 5 f. Wave w owns dsub {2w, 2w+1} for all 5 f.
__global__ __launch_bounds__(256, 3) void k_gemm2_out(
        const unsigned short* __restrict__ xxx,
        const unsigned short* __restrict__ w2t,
        const float* __restrict__ x,
        const float* __restrict__ state,
        const float* __restrict__ mk,
        const float* __restrict__ mw,
        const float* __restrict__ mv,
        const float* __restrict__ mr,
        const float* __restrict__ mg,
        const int* __restrict__ pi,
        float* __restrict__ out) {
    __shared__ float res[5 * 16 * 132];   // row stride 132 words
    int tid = threadIdx.x;
    int w = tid >> 6, lane = tid & 63;
    int q = lane >> 4, nl = lane & 15;
    int tokTile = blockIdx.x >> 4;
    int dTile   = blockIdx.x & 15;
    int m0 = tokTile * 16;
    int d0 = dTile * 128;
    int i1 = 66 * pi[0] + 1;
    int b     = m0 >> 11;
    int sbase = m0 & (SLEN - 1);

    // ---- epilogue prefetch: independent of MFMA phase, issue FIRST ----
    // thread -> (tok0, dv0) with tok1 = tok0+8 for the second half
    int tok0 = tid >> 5;
    int dv0  = (tid & 31) * 4;
    int s0   = sbase + tok0;
    int dA   = d0 + dv0;
    size_t xoff0 = ((size_t)(b * SLEN + s0)) * DDIM + dA;
    size_t xoff1 = xoff0 + (size_t)8 * DDIM;           // tok0+8, never the s==0 row
    f32x4 xv0 = *(const f32x4*)(x + xoff0);
    f32x4 pv0 = (s0 == 0)
        ? *(const f32x4*)(state + ((size_t)(b * SROWS + i1)) * DDIM + dA)
        : *(const f32x4*)(x + xoff0 - DDIM);
    f32x4 xv1 = *(const f32x4*)(x + xoff1);
    f32x4 pv1 = *(const f32x4*)(x + xoff1 - DDIM);

    // ---- MFMA phase: preload all frags (static indexing), then compute ----
    bf16x8 af[5];
    const unsigned short* arow = xxx + (size_t)(m0 + nl) * RANK + q * 8;
    #pragma unroll
    for (int f = 0; f < 5; f++)
        af[f] = *(const bf16x8*)(arow + f * 32);
    bf16x8 bfr[5][2];
    #pragma unroll
    for (int f = 0; f < 5; f++)
        #pragma unroll
        for (int j = 0; j < 2; j++) {
            int dsub = w * 2 + j;
            bfr[f][j] = *(const bf16x8*)(w2t + ((size_t)(f * DDIM) + d0 + dsub * 16 + nl) * 32
                                         + q * 8);
        }
    #pragma unroll
    for (int f = 0; f < 5; f++)
        #pragma unroll
        for (int j = 0; j < 2; j++) {
            int dsub = w * 2 + j;
            f32x4 c = (f32x4){0.f, 0.f, 0.f, 0.f};
            c = __builtin_amdgcn_mfma_f32_16x16x32_bf16(af[f], bfr[f][j], c, 0, 0, 0);
            #pragma unroll
            for (int r = 0; r < 4; r++)
                res[(f * 16 + q * 4 + r) * 132 + dsub * 16 + nl] = c[r];
        }
    __syncthreads();

    // ---- epilogue: vec4, NT stores ----
    size_t obase0 = ((size_t)((b * SLEN + s0) * 5)) * DDIM + dA;
    size_t obase1 = obase0 + (size_t)8 * 5 * DDIM;
    #pragma unroll
    for (int f = 0; f < 5; f++) {
        const float* maa = (f == 0) ? mk : (f == 1) ? mw : (f == 2) ? mv
                         : (f == 3) ? mr : mg;
        f32x4 mvv = *(const f32x4*)(maa + dA);
        f32x4 r0  = *(const f32x4*)&res[(f * 16 + tok0) * 132 + dv0];
        f32x4 r1  = *(const f32x4*)&res[(f * 16 + tok0 + 8) * 132 + dv0];
        f32x4 o0, o1;
        #pragma unroll
        for (int j = 0; j < 4; j++) {
            o0[j] = xv0[j] + (pv0[j] - xv0[j]) * (mvv[j] + r0[j]);
            o1[j] = xv1[j] + (pv1[j] - xv1[j]) * (mvv[j] + r1[j]);
        }
        __builtin_nontemporal_store(o0, (f32x4*)(out + obase0 + (size_t)f * DDIM));
        __builtin_nontemporal_store(o1, (f32x4*)(out + obase1 + (size_t)f * DDIM));
    }
}

extern "C" void kernel_launch(void* const* d_in, const int* in_sizes, int n_in,
                              void* d_out, int out_size, void* d_ws, size_t ws_size,
                              hipStream_t stream) {
    const float* x   = (const float*)d_in[0];
    const float* st  = (const float*)d_in[1];
    const float* tmx = (const float*)d_in[2];
    const float* w1  = (const float*)d_in[3];
    const float* w2  = (const float*)d_in[4];
    const float* mk  = (const float*)d_in[5];
    const float* mw  = (const float*)d_in[6];
    const float* mv  = (const float*)d_in[7];
    const float* mr  = (const float*)d_in[8];
    const float* mg  = (const float*)d_in[9];
    const int* pi    = (const int*)d_in[10];
    float* out = (float*)d_out;

    // ws usage: 3,932,160 bytes total
    char* ws = (char*)d_ws;
    unsigned short* xxx = (unsigned short*)(ws);                    // 2,621,440 B
    unsigned short* w1t = (unsigned short*)(ws + 2621440);          //   655,360 B
    unsigned short* w2t = (unsigned short*)(ws + 2621440 + 655360); //   655,360 B

    k_prep<<<1168, 256, 0, stream>>>(x, st, pi, w1, w2, out + OUT_MAIN, w1t, w2t);
    k_gemm1f<<<512, 640, 0, stream>>>(x, st, tmx, w1t, pi, xxx);
    k_gemm2_out<<<8192, 256, 0, stream>>>(xxx, w2t, x, st, mk, mw, mv, mr, mg, pi, out);
}